// Round 7
// baseline (231.150 us; speedup 1.0000x reference)
//
#include <hip/hip_runtime.h>
#include <hip/hip_fp16.h>

#define NN 100000
#define NE 1600000
#define FIN 128
#define HD 64
#define CO 40
#define NG 2048
#define NSB 196           // super-buckets of 512 nodes: ceil(100000/512)
#define SCAP 9216         // super-bucket capacity (mean 8163, +11 sigma)
#define GCAP 13312        // padded ssrc capacity per group (SCAP + 512*7 pad)
#define CHUNK 4096        // edges per scatter block
#define NSCAT ((NE + CHUNK - 1) / CHUNK)   // 391

typedef _Float16 half8 __attribute__((ext_vector_type(8)));
typedef float floatx4 __attribute__((ext_vector_type(4)));

union RowU { float4 f4; __half2 h2[4]; };

// ---------------- setup: cursors + zero readout + zero dummy rows + weight prep ----------------
__global__ __launch_bounds__(256) void setup_kernel(int* __restrict__ scur,
                                                    float* __restrict__ readout,
                                                    unsigned int* __restrict__ dummy,
                                                    unsigned int* __restrict__ dummy2,
                                                    const float* __restrict__ pre_w,
                                                    const float* __restrict__ pre_b,
                                                    const float* __restrict__ c1_w,
                                                    const float* __restrict__ c2_w,
                                                    _Float16* __restrict__ wth,
                                                    float* __restrict__ beff,
                                                    _Float16* __restrict__ wt2h) {
    int b = blockIdx.x;
    if (b < 512) {
        int gid = b * 256 + threadIdx.x;
        if (gid < NG * HD) readout[gid] = 0.0f;
        if (gid < NSB) scur[gid * 16] = gid * SCAP;
        if (gid < HD / 2) { dummy[gid] = 0u; dummy2[gid] = 0u; }   // 64 halves = 32 uints each
        return;
    }
    b -= 512;
    if (b < 32) {
        int o = b * 256 + threadIdx.x;
        int r = o >> 6, c = o & 63;
        float acc = 0.0f;
#pragma unroll 8
        for (int k = 0; k < HD; k++) acc = fmaf(pre_w[r * HD + k], c1_w[k * HD + c], acc);
        wth[c * FIN + r] = (_Float16)acc;
    } else if (b == 32) {
        int c = threadIdx.x;
        if (c < HD) {
            float acc = 0.0f;
#pragma unroll 8
            for (int k = 0; k < HD; k++) acc = fmaf(pre_b[k], c1_w[k * HD + c], acc);
            beff[c] = acc;
        }
    } else {
        int o = (b - 33) * 256 + threadIdx.x;   // 0..4095
        int r = o >> 6, c = o & 63;
        wt2h[c * HD + r] = (_Float16)c2_w[o];
    }
}

// =====================================================================
// P1: binned scatter into 196 super-buckets (512 nodes each).
// 1024 threads/block, (dst,src) register-cached across phases (R13).
// =====================================================================
__global__ __launch_bounds__(1024) void scatter_super(const int* __restrict__ src,
                                                      const int* __restrict__ dst,
                                                      int* __restrict__ scur,
                                                      unsigned int* __restrict__ stmp) {
    __shared__ int hist[NSB];
    __shared__ int gbase[NSB];
    int tid = threadIdx.x;
    int e0 = blockIdx.x * CHUNK;
    int d[4], s[4];
    if (tid < NSB) hist[tid] = 0;
    __syncthreads();
#pragma unroll
    for (int r = 0; r < 4; r++) {
        int e = e0 + tid + r * 1024;
        d[r] = -1; s[r] = 0;
        if (e < NE) {
            d[r] = dst[e];
            s[r] = src[e];
            atomicAdd(&hist[d[r] >> 9], 1);
        }
    }
    __syncthreads();
    if (tid < NSB) {
        int c = hist[tid];
        gbase[tid] = (c > 0) ? atomicAdd(&scur[tid * 16], c) : 0;
        hist[tid] = 0;
    }
    __syncthreads();
#pragma unroll
    for (int r = 0; r < 4; r++) {
        if (d[r] >= 0) {
            int b = d[r] >> 9;
            int p = atomicAdd(&hist[b], 1);
            stmp[gbase[b] + p] = ((unsigned int)(d[r] & 511) << 17) | (unsigned int)s[r];
        }
    }
}

// =====================================================================
// P2: per-super-bucket counting sort (512 node bins) -> padded ssrc,
// offs/degn/di. R19: ALSO emits a bucket-local degree-class permutation
// perm[] (16 classes of nit=pd/8) so gather waves get 8 SAME-CLASS nodes
// -> wave row-phase time ~ mean degree instead of max-of-8 (~1.7x).
// perm is dense over [0,NN): all buckets except the last are full.
// =====================================================================
__global__ __launch_bounds__(1024) void group_sort(const int* __restrict__ scur,
                                                   const unsigned int* __restrict__ stmp,
                                                   unsigned int* __restrict__ ssrc,
                                                   int* __restrict__ offs,
                                                   int* __restrict__ degn,
                                                   float* __restrict__ di,
                                                   int* __restrict__ perm) {
    __shared__ int lh[512];
    __shared__ int sc[512];
    __shared__ int lcur[512];
    __shared__ int ch[16];
    __shared__ int cbase[16];
    int g = blockIdx.x;
    int tid = threadIdx.x;
    int base = g * SCAP;
    int cnt = scur[g * 16] - base;
    if (tid < 512) lh[tid] = 0;
    if (tid < 16) ch[tid] = 0;
    __syncthreads();
    unsigned int uv[9];          // SCAP/1024 == 9 exactly
#pragma unroll
    for (int r = 0; r < 9; r++) {
        int i = tid + r * 1024;
        uv[r] = 0xFFFFFFFFu;     // valid entries are < 2^26, sentinel safe
        if (i < cnt) {
            uv[r] = stmp[base + i];
            atomicAdd(&lh[uv[r] >> 17], 1);
        }
    }
    __syncthreads();
    int h = 0, pd = 0, cls = 0, cpos = 0;
    if (tid < 512) {
        h = lh[tid];
        pd = (h + 7) & ~7;
        sc[tid] = pd;
        if (g * 512 + tid < NN) {
            cls = pd >> 3; if (cls > 15) cls = 15;
            cpos = atomicAdd(&ch[cls], 1);
        }
    }
    __syncthreads();
    for (int off = 1; off < 512; off <<= 1) {
        int v = 0;
        if (tid >= off && tid < 512) v = sc[tid - off];
        __syncthreads();
        if (tid < 512) sc[tid] += v;
        __syncthreads();
    }
    if (tid < 512) {
        int excl = sc[tid] - pd;    // exclusive scan of padded counts
        lcur[tid] = excl;
        int node = g * 512 + tid;
        if (node < NN) {
            offs[node] = g * GCAP + excl;
            degn[node] = pd;
            di[node] = rsqrtf((float)h + 1.0f);
        }
        size_t gb = (size_t)g * GCAP;
        for (int q = h; q < pd; q++) ssrc[gb + excl + q] = (unsigned int)NN;  // pads -> zero row
    }
    if (tid == 0) {
        int run = 0;
#pragma unroll
        for (int i = 0; i < 16; i++) { cbase[i] = run; run += ch[i]; }
    }
    __syncthreads();
    if (tid < 512) {
        int node = g * 512 + tid;
        if (node < NN) perm[g * 512 + cbase[cls] + cpos] = node;   // dense: full buckets
    }
#pragma unroll
    for (int r = 0; r < 9; r++) {
        unsigned int u = uv[r];
        if (u != 0xFFFFFFFFu) {
            int dl = (int)(u >> 17);
            int pos = atomicAdd(&lcur[dl], 1);
            ssrc[(size_t)g * GCAP + pos] = u & 0x1FFFFu;
        }
    }
}

// =====================================================================
// R15: MFMA GEMM 1: hws = half((x @ W_eff + b_eff) * di)  [N,128]@[128,64]
// W^T fp16 held ENTIRELY in per-wave registers -> A streams HBM->MFMA.
// =====================================================================
__global__ __launch_bounds__(256, 4) void gemm1_mfma(const float* __restrict__ x,
                                                     const _Float16* __restrict__ wt,
                                                     const float* __restrict__ beff,
                                                     const float* __restrict__ di,
                                                     __half* __restrict__ hws) {
    __shared__ _Float16 wS[64 * 136];   // [n][k] padded 128->136 (bank-spread)
    int tid = threadIdx.x;
    for (int i = tid; i < 1024; i += 256) {          // 1024 x uint4 = 8192 halves
        int n = i >> 4, k0 = (i & 15) * 8;
        *(uint4*)&wS[n * 136 + k0] = ((const uint4*)wt)[i];
    }
    __syncthreads();
    int wv = tid >> 6, lane = tid & 63;
    int l15 = lane & 15, lg = lane >> 4;
    int rbase = blockIdx.x * 64 + wv * 16;
    if (rbase >= NN) return;                         // NN%16==0: whole-tile skip only
    half8 bf[4][4];                                  // [ks][ns] B-fragments (W), 64 VGPR
#pragma unroll
    for (int ks = 0; ks < 4; ks++)
#pragma unroll
        for (int ns = 0; ns < 4; ns++)
            bf[ks][ns] = *(const half8*)&wS[(ns * 16 + l15) * 136 + ks * 32 + lg * 8];
    floatx4 acc[4];
#pragma unroll
    for (int ns = 0; ns < 4; ns++) acc[ns] = (floatx4){0.f, 0.f, 0.f, 0.f};
    const float* xrow = x + (size_t)(rbase + l15) * FIN;
#pragma unroll
    for (int ks = 0; ks < 4; ks++) {
        float4 lo = *(const float4*)(xrow + ks * 32 + lg * 8);
        float4 hi = *(const float4*)(xrow + ks * 32 + lg * 8 + 4);
        half8 a;
        a[0] = (_Float16)lo.x; a[1] = (_Float16)lo.y; a[2] = (_Float16)lo.z; a[3] = (_Float16)lo.w;
        a[4] = (_Float16)hi.x; a[5] = (_Float16)hi.y; a[6] = (_Float16)hi.z; a[7] = (_Float16)hi.w;
#pragma unroll
        for (int ns = 0; ns < 4; ns++)
            acc[ns] = __builtin_amdgcn_mfma_f32_16x16x32_f16(a, bf[ks][ns], acc[ns], 0, 0, 0);
    }
    int r0 = rbase + lg * 4;
#pragma unroll
    for (int ns = 0; ns < 4; ns++) {
        float be = beff[ns * 16 + l15];
#pragma unroll
        for (int r = 0; r < 4; r++) {
            float dn = di[r0 + r];
            hws[(size_t)(r0 + r) * HD + ns * 16 + l15] = __float2half((acc[ns][r] + be) * dn);
        }
    }
}

// ---------------- gather helpers ----------------
__device__ __forceinline__ RowU ldrow(const __half* __restrict__ hws, unsigned int idx, int fp) {
    RowU r;
    r.f4 = ((const float4*)(hws + (size_t)idx * HD))[fp];
    return r;
}

// R17: spill-proof double-buffered gather core (separately-named scalars,
// unconditional loads in each arm; 16 rows transiently in flight).
#define LDA8(A, B) { u0 = ldrow(hws, (A).x, fp); u1 = ldrow(hws, (A).y, fp); \
                     u2 = ldrow(hws, (A).z, fp); u3 = ldrow(hws, (A).w, fp); \
                     u4 = ldrow(hws, (B).x, fp); u5 = ldrow(hws, (B).y, fp); \
                     u6 = ldrow(hws, (B).z, fp); u7 = ldrow(hws, (B).w, fp); }
#define LDB8(A, B) { v0 = ldrow(hws, (A).x, fp); v1 = ldrow(hws, (A).y, fp); \
                     v2 = ldrow(hws, (A).z, fp); v3 = ldrow(hws, (A).w, fp); \
                     v4 = ldrow(hws, (B).x, fp); v5 = ldrow(hws, (B).y, fp); \
                     v6 = ldrow(hws, (B).z, fp); v7 = ldrow(hws, (B).w, fp); }
#define ACC4(Q, U) { hacc[Q][0] = __hadd2(hacc[Q][0], (U).h2[0]); \
                     hacc[Q][1] = __hadd2(hacc[Q][1], (U).h2[1]); \
                     hacc[Q][2] = __hadd2(hacc[Q][2], (U).h2[2]); \
                     hacc[Q][3] = __hadd2(hacc[Q][3], (U).h2[3]); }
#define ACCA8() { ACC4(0, u0) ACC4(1, u1) ACC4(2, u2) ACC4(3, u3) \
                  ACC4(0, u4) ACC4(1, u5) ACC4(2, u6) ACC4(3, u7) }
#define ACCB8() { ACC4(0, v0) ACC4(1, v1) ACC4(2, v2) ACC4(3, v3) \
                  ACC4(0, v4) ACC4(1, v5) ACC4(2, v6) ACC4(3, v7) }

__device__ __forceinline__ void gather_node8(const int* __restrict__ offs,
                                             const int* __restrict__ pdeg,
                                             const unsigned int* __restrict__ ssrc,
                                             const __half* __restrict__ hws,
                                             int node, int fp, float acc[8]) {
    int i0 = offs[node];
    int deg = pdeg[node];                    // multiple of 8 (may be 0)
    const uint4* ip = (const uint4*)(ssrc + i0);     // 16B-aligned (offs multiple of 8)
    __half2 hacc[4][4];
#pragma unroll
    for (int s = 0; s < 4; s++)
#pragma unroll
        for (int t = 0; t < 4; t++) hacc[s][t] = __floats2half2_rn(0.f, 0.f);
    // self-loop row
    {
        RowU sl = ldrow(hws, (unsigned int)node, fp);
#pragma unroll
        for (int t = 0; t < 4; t++) hacc[0][t] = sl.h2[t];
    }
    int nit = deg >> 3;
    if (nit > 0) {
        RowU u0, u1, u2, u3, u4, u5, u6, u7;
        RowU v0, v1, v2, v3, v4, v5, v6, v7;
        {
            uint4 a = ip[0], b = ip[1];
            LDA8(a, b);
        }
        int it = 1;
        for (; it + 1 < nit; it += 2) {
            uint4 a1 = ip[2 * it], b1 = ip[2 * it + 1];
            LDB8(a1, b1);           // it-th tile loads in flight over ACCA
            ACCA8();
            uint4 a2 = ip[2 * it + 2], b2 = ip[2 * it + 3];
            LDA8(a2, b2);           // (it+1)-th tile loads in flight over ACCB
            ACCB8();
        }
        if (it < nit) {             // one trailing pair: load B, consume A then B
            uint4 a1 = ip[2 * it], b1 = ip[2 * it + 1];
            LDB8(a1, b1);
            ACCA8();
            ACCB8();
        } else {
            ACCA8();
        }
    }
    // combine the 4 half2 sets in fp32
#pragma unroll
    for (int t = 0; t < 4; t++) {
        float2 a = __half22float2(hacc[0][t]);
        float2 b = __half22float2(hacc[1][t]);
        float2 c = __half22float2(hacc[2][t]);
        float2 d = __half22float2(hacc[3][t]);
        acc[2 * t]     = (a.x + b.x) + (c.x + d.x);
        acc[2 * t + 1] = (a.y + b.y) + (c.y + d.y);
    }
}

// LN over the 8-features-per-lane layout; xor 1,2,4 stays inside the
// 8-lane group (lane bits 0..2 == fp). Returns relu'd y[8].
__device__ __forceinline__ void ln8(float v[8], int fp,
                                    const float* __restrict__ g,
                                    const float* __restrict__ bb,
                                    float y[8]) {
    float su = 0.0f;
#pragma unroll
    for (int t = 0; t < 8; t++) su += v[t];
    su += __shfl_xor(su, 1, 64); su += __shfl_xor(su, 2, 64); su += __shfl_xor(su, 4, 64);
    float mu = su * (1.0f / HD);
    float q = 0.0f;
#pragma unroll
    for (int t = 0; t < 8; t++) { float d = v[t] - mu; q += d * d; }
    q += __shfl_xor(q, 1, 64); q += __shfl_xor(q, 2, 64); q += __shfl_xor(q, 4, 64);
    float rstd = rsqrtf(q * (1.0f / HD) + 1e-5f);
    float4 ga = ((const float4*)g)[fp * 2], gb = ((const float4*)g)[fp * 2 + 1];
    float4 ba = ((const float4*)bb)[fp * 2], bc = ((const float4*)bb)[fp * 2 + 1];
    float gv[8] = {ga.x, ga.y, ga.z, ga.w, gb.x, gb.y, gb.z, gb.w};
    float bv[8] = {ba.x, ba.y, ba.z, ba.w, bc.x, bc.y, bc.z, bc.w};
#pragma unroll
    for (int t = 0; t < 8; t++) y[t] = fmaxf((v[t] - mu) * rstd * gv[t] + bv[t], 0.0f);
}

// =====================================================================
// R18 FUSED layer-1 gather + LN + ReLU -> h1, THEN conv2 MFMA -> hws2.
// R19: nodes come from the degree-class perm (balanced waves AND a
// balanced pre-barrier block). Node IDs staged in pnS for the conv
// epilogue's scattered row writes.
// =====================================================================
__global__ __launch_bounds__(256, 4) void gather_ln_conv(const int* __restrict__ perm,
                                                         const int* __restrict__ offs,
                                                         const int* __restrict__ pdeg,
                                                         const unsigned int* __restrict__ ssrc,
                                                         const float* __restrict__ di,
                                                         const __half* __restrict__ hws,
                                                         const float* __restrict__ cb,
                                                         const float* __restrict__ g,
                                                         const float* __restrict__ bb,
                                                         const _Float16* __restrict__ wt2,
                                                         __half* __restrict__ h1out,
                                                         __half* __restrict__ hws2) {
    __shared__ _Float16 wS2[64 * 72];   // c2_w^T [n][k] padded
    __shared__ _Float16 yS[32 * 80];    // 32 y-rows, stride 80
    __shared__ int pnS[32];             // the 32 node IDs (for conv row writes)
    int tid = threadIdx.x;
    for (int i = tid; i < 512; i += 256) {           // stage c2_w^T early
        int n = i >> 3, k0 = (i & 7) * 8;
        *(uint4*)&wS2[n * 72 + k0] = ((const uint4*)wt2)[i];
    }
    int wv = tid >> 6;
    int lane = tid & 63;
    int fp = lane & 7, gg = lane >> 3;
    int l15 = lane & 15, lg = lane >> 4;
    int node = perm[blockIdx.x * 32 + wv * 8 + gg];   // NN % 32 == 0, perm dense
    if (fp == 0) pnS[wv * 8 + gg] = node;
    float acc[8];
    gather_node8(offs, pdeg, ssrc, hws, node, fp, acc);
    float4 ca = ((const float4*)cb)[fp * 2], cc = ((const float4*)cb)[fp * 2 + 1];
    float cv[8] = {ca.x, ca.y, ca.z, ca.w, cc.x, cc.y, cc.z, cc.w};
    float dn = di[node];
    float v[8], y[8];
#pragma unroll
    for (int t = 0; t < 8; t++) v[t] = acc[t] * dn + cv[t];
    ln8(v, fp, g, bb, y);
    union U { float4 f4; __half2 h2[4]; } u;
#pragma unroll
    for (int t = 0; t < 4; t++) u.h2[t] = __floats2half2_rn(y[2 * t], y[2 * t + 1]);
    ((float4*)(h1out + (size_t)node * HD))[fp] = u.f4;   // row write (128B granule)
    *(float4*)&yS[(wv * 8 + gg) * 80 + fp * 8] = u.f4;   // same bits into LDS
    __syncthreads();
    // ---- conv2 MFMA phase: wave wv -> tile (wv&1), ns pair (wv>>1)*2 ----
    int tile = wv & 1;
    int nsb = (wv >> 1) * 2;
    half8 bf2[2][2];
#pragma unroll
    for (int ks = 0; ks < 2; ks++)
#pragma unroll
        for (int n = 0; n < 2; n++)
            bf2[ks][n] = *(const half8*)&wS2[((nsb + n) * 16 + l15) * 72 + ks * 32 + lg * 8];
    floatx4 acc2[2];
    acc2[0] = (floatx4){0.f, 0.f, 0.f, 0.f};
    acc2[1] = (floatx4){0.f, 0.f, 0.f, 0.f};
    const _Float16* yrow = &yS[(tile * 16 + l15) * 80];
#pragma unroll
    for (int ks = 0; ks < 2; ks++) {
        half8 a = *(const half8*)(yrow + ks * 32 + lg * 8);
#pragma unroll
        for (int n = 0; n < 2; n++)
            acc2[n] = __builtin_amdgcn_mfma_f32_16x16x32_f16(a, bf2[ks][n], acc2[n], 0, 0, 0);
    }
#pragma unroll
    for (int r = 0; r < 4; r++) {
        int nodeR = pnS[tile * 16 + lg * 4 + r];
        float d2 = di[nodeR];
#pragma unroll
        for (int n = 0; n < 2; n++)
            hws2[(size_t)nodeR * HD + (nsb + n) * 16 + l15] = __float2half(acc2[n][r] * d2);
    }
}

// ---------------- layer-2 gather (8 nodes/wave) + LN + ReLU + skip + pooled scatter ----------------
// R19: perm'd nodes -> lb rows are mostly distinct groups; run-merge path
// handles arbitrary order (correct via atomics, merges equal-adjacent).
__global__ __launch_bounds__(256, 4) void gather_ln_pool(const int* __restrict__ perm,
                                                         const int* __restrict__ offs,
                                                         const int* __restrict__ pdeg,
                                                         const unsigned int* __restrict__ ssrc,
                                                         const float* __restrict__ di,
                                                         const __half* __restrict__ hws,
                                                         const float* __restrict__ cb,
                                                         const float* __restrict__ g,
                                                         const float* __restrict__ bb,
                                                         const __half* __restrict__ h1,
                                                         const int* __restrict__ batch,
                                                         float* __restrict__ readout) {
    __shared__ float ls[32][65];
    __shared__ int lb[32];
    int wv = threadIdx.x >> 6;
    int lane = threadIdx.x & 63;
    int fp = lane & 7, gg = lane >> 3;
    int node = perm[blockIdx.x * 32 + wv * 8 + gg];
    float acc[8];
    gather_node8(offs, pdeg, ssrc, hws, node, fp, acc);
    float4 ca = ((const float4*)cb)[fp * 2], cc = ((const float4*)cb)[fp * 2 + 1];
    float cv[8] = {ca.x, ca.y, ca.z, ca.w, cc.x, cc.y, cc.z, cc.w};
    float dn = di[node];
    float v[8], y[8];
#pragma unroll
    for (int t = 0; t < 8; t++) v[t] = acc[t] * dn + cv[t];
    ln8(v, fp, g, bb, y);
    // skip connection: s = relu(ln(conv2)) + h1
    union U { float4 f4; __half2 h2[4]; } u;
    u.f4 = ((const float4*)(h1 + (size_t)node * HD))[fp];
    int row = wv * 8 + gg;
#pragma unroll
    for (int t = 0; t < 4; t++) {
        float2 p = __half22float2(u.h2[t]);
        ls[row][fp * 8 + 2 * t]     = y[2 * t] + p.x;
        ls[row][fp * 8 + 2 * t + 1] = y[2 * t + 1] + p.y;
    }
    if (fp == 0) lb[row] = batch[node];
    // rows of this wave are wave-private: per-wave DS ordering suffices, no __syncthreads
    int r0 = wv * 8;
    int bu = lb[r0];
    bool uni = true;
#pragma unroll
    for (int r = 1; r < 8; r++) uni = uni && (lb[r0 + r] == bu);
    int f = lane;
    if (uni) {
        float s2 = 0.0f;
#pragma unroll
        for (int r = 0; r < 8; r++) s2 += ls[r0 + r][f];
        atomicAdd(&readout[(size_t)bu * HD + f], s2);   // 64-lane contiguous
    } else {
        // merge equal-adjacent runs (arbitrary order is still correct)
        float s2 = ls[r0][f];
        int bprev = lb[r0];
#pragma unroll
        for (int r = 1; r < 8; r++) {
            int bn = lb[r0 + r];
            if (bn == bprev) {
                s2 += ls[r0 + r][f];
            } else {
                atomicAdd(&readout[(size_t)bprev * HD + f], s2);
                s2 = ls[r0 + r][f];
                bprev = bn;
            }
        }
        atomicAdd(&readout[(size_t)bprev * HD + f], s2);
    }
}

// ---------------- final: out = readout @ post_w + post_b  [G,64]@[64,40] ----------------
__global__ __launch_bounds__(256) void out_gemm(const float* __restrict__ r,
                                                const float* __restrict__ w,
                                                const float* __restrict__ b,
                                                float* __restrict__ out) {
    __shared__ float lw[HD * CO];
    for (int i = threadIdx.x; i < HD * CO; i += 256) lw[i] = w[i];
    __syncthreads();
    int grp = blockIdx.x * 4 + (threadIdx.x >> 6);
    int c = threadIdx.x & 63;
    if (grp >= NG || c >= CO) return;
    const float* rr = r + (size_t)grp * HD;
    float acc = b[c];
#pragma unroll 8
    for (int k = 0; k < HD; k++) acc = fmaf(rr[k], lw[k * CO + c], acc);
    out[(size_t)grp * CO + c] = acc;
}

extern "C" void kernel_launch(void* const* d_in, const int* in_sizes, int n_in,
                              void* d_out, int out_size, void* d_ws, size_t ws_size,
                              hipStream_t stream) {
    const float* x      = (const float*)d_in[0];
    const int*   ei     = (const int*)d_in[1];
    const int*   batch  = (const int*)d_in[2];
    const float* pre_w  = (const float*)d_in[3];
    const float* pre_b  = (const float*)d_in[4];
    const float* c1_w   = (const float*)d_in[5];
    const float* c1_b   = (const float*)d_in[6];
    const float* n1_g   = (const float*)d_in[7];
    const float* n1_b   = (const float*)d_in[8];
    const float* c2_w   = (const float*)d_in[9];
    const float* c2_b   = (const float*)d_in[10];
    const float* n2_g   = (const float*)d_in[11];
    const float* n2_b   = (const float*)d_in[12];
    const float* post_w = (const float*)d_in[13];
    const float* post_b = (const float*)d_in[14];

    const int* src = ei;
    const int* dst = ei + NE;

    char* p = (char*)d_ws;
    int*          scur    = (int*)p;          p += (size_t)NSB * 16 * 4;
    int*          offs    = (int*)p;          p += (size_t)NN * 4;
    int*          degn    = (int*)p;          p += (size_t)NN * 4;
    float*        di      = (float*)p;        p += (size_t)NN * 4;
    int*          perm    = (int*)p;          p += (size_t)NN * 4;
    _Float16*     wth     = (_Float16*)p;     p += (size_t)FIN * HD * 2;   // W_eff^T fp16
    _Float16*     wt2h    = (_Float16*)p;     p += (size_t)HD * HD * 2;    // c2_w^T fp16
    float*        beff    = (float*)p;        p += 256;
    unsigned int* stmp    = (unsigned int*)p; p += (size_t)NSB * SCAP * 4;
    unsigned int* ssrc    = (unsigned int*)p; p += (size_t)NSB * GCAP * 4;
    float*        readout = (float*)p;        p += (size_t)NG * HD * 4;
    __half*       hws     = (__half*)p;       p += (size_t)(NN + 8) * HD * 2;  // +dummy row
    __half*       hws2    = (__half*)p;       p += (size_t)(NN + 8) * HD * 2;  // conv2 out +dummy
    __half*       h1      = (__half*)p;       p += (size_t)NN * HD * 2;

    // setup (cursors, readout zero, dummy rows) + folded weight prep (blocks 512..560)
    setup_kernel<<<561, 256, 0, stream>>>(scur, readout,
                                          (unsigned int*)(hws + (size_t)NN * HD),
                                          (unsigned int*)(hws2 + (size_t)NN * HD),
                                          pre_w, pre_b, c1_w, c2_w, wth, beff, wt2h);

    // two-level CSR build: super-bucket scatter -> per-group counting sort (+degree perm)
    scatter_super<<<NSCAT, 1024, 0, stream>>>(src, dst, scur, stmp);
    group_sort<<<NSB, 1024, 0, stream>>>(scur, stmp, ssrc, offs, degn, di, perm);

    // layer 1 GEMM
    gemm1_mfma<<<(NN + 63) / 64, 256, 0, stream>>>(x, wth, beff, di, hws);

    // fused: layer-1 gather + LN + ReLU -> h1, then conv2 MFMA -> hws2
    gather_ln_conv<<<NN / 32, 256, 0, stream>>>(perm, offs, degn, ssrc, di, hws,
                                                c1_b, n1_g, n1_b, wt2h, h1, hws2);

    // layer 2 gather + LN + ReLU + skip + pooled scatter
    gather_ln_pool<<<NN / 32, 256, 0, stream>>>(perm, offs, degn, ssrc, di, hws2,
                                                c2_b, n2_g, n2_b, h1, batch, readout);

    out_gemm<<<(NG + 3) / 4, 256, 0, stream>>>(readout, post_w, post_b, (float*)d_out);
}

// Round 8
// 228.421 us; speedup vs baseline: 1.0119x; 1.0119x over previous
//
#include <hip/hip_runtime.h>
#include <hip/hip_fp16.h>

#define NN 100000
#define NE 1600000
#define FIN 128
#define HD 64
#define CO 40
#define NG 2048
#define NSB 196           // super-buckets of 512 nodes: ceil(100000/512)
#define SCAP 9216         // super-bucket capacity (mean 8163, +11 sigma)
#define GCAP 13312        // padded ssrc capacity per group (SCAP + 512*7 pad)
#define CHUNK 4096        // edges per scatter block
#define NSCAT ((NE + CHUNK - 1) / CHUNK)   // 391

typedef _Float16 half8 __attribute__((ext_vector_type(8)));
typedef float floatx4 __attribute__((ext_vector_type(4)));

union RowU { float4 f4; __half2 h2[4]; };

// ---------------- setup: cursors + zero readout + zero dummy rows ----------------
__global__ __launch_bounds__(256) void setup_kernel(int* __restrict__ scur,
                                                    float* __restrict__ readout,
                                                    unsigned int* __restrict__ dummy,
                                                    unsigned int* __restrict__ dummy2) {
    int gid = blockIdx.x * 256 + threadIdx.x;
    if (gid < NG * HD) readout[gid] = 0.0f;
    if (gid < NSB) scur[gid * 16] = gid * SCAP;
    if (gid < HD / 2) { dummy[gid] = 0u; dummy2[gid] = 0u; }   // 64 halves = 32 uints each
}

// =====================================================================
// P1: binned scatter into 196 super-buckets (512 nodes each).
// 1024 threads/block, (dst,src) register-cached across phases (R13).
// R20: weight prep (wth/beff/wt2h) folded in as 9 trailing blocks —
// depends only on kernel inputs, hides fully under the scatter.
// =====================================================================
__global__ __launch_bounds__(1024) void scatter_super(const int* __restrict__ src,
                                                      const int* __restrict__ dst,
                                                      int* __restrict__ scur,
                                                      unsigned int* __restrict__ stmp,
                                                      const float* __restrict__ pre_w,
                                                      const float* __restrict__ pre_b,
                                                      const float* __restrict__ c1_w,
                                                      const float* __restrict__ c2_w,
                                                      _Float16* __restrict__ wth,
                                                      float* __restrict__ beff,
                                                      _Float16* __restrict__ wt2h) {
    if (blockIdx.x >= NSCAT) {
        int i = blockIdx.x - NSCAT;
        int tid = threadIdx.x;
        if (i < 8) {
            int o = i * 1024 + tid;          // 8192 wth elements
            int r = o >> 6, c = o & 63;
            float acc = 0.0f;
#pragma unroll 8
            for (int k = 0; k < HD; k++) acc = fmaf(pre_w[r * HD + k], c1_w[k * HD + c], acc);
            wth[c * FIN + r] = (_Float16)acc;
        } else {
#pragma unroll
            for (int j = 0; j < 4; j++) {    // 4096 wt2h elements
                int o = tid + j * 1024;
                int r = o >> 6, c = o & 63;
                wt2h[c * HD + r] = (_Float16)c2_w[o];
            }
            if (tid < HD) {
                float acc = 0.0f;
#pragma unroll 8
                for (int k = 0; k < HD; k++) acc = fmaf(pre_b[k], c1_w[k * HD + tid], acc);
                beff[tid] = acc;
            }
        }
        return;
    }
    __shared__ int hist[NSB];
    __shared__ int gbase[NSB];
    int tid = threadIdx.x;
    int e0 = blockIdx.x * CHUNK;
    int d[4], s[4];
    if (tid < NSB) hist[tid] = 0;
    __syncthreads();
#pragma unroll
    for (int r = 0; r < 4; r++) {
        int e = e0 + tid + r * 1024;
        d[r] = -1; s[r] = 0;
        if (e < NE) {
            d[r] = dst[e];
            s[r] = src[e];
            atomicAdd(&hist[d[r] >> 9], 1);
        }
    }
    __syncthreads();
    if (tid < NSB) {
        int c = hist[tid];
        gbase[tid] = (c > 0) ? atomicAdd(&scur[tid * 16], c) : 0;
        hist[tid] = 0;
    }
    __syncthreads();
#pragma unroll
    for (int r = 0; r < 4; r++) {
        if (d[r] >= 0) {
            int b = d[r] >> 9;
            int p = atomicAdd(&hist[b], 1);
            stmp[gbase[b] + p] = ((unsigned int)(d[r] & 511) << 17) | (unsigned int)s[r];
        }
    }
}

// =====================================================================
// P2: per-super-bucket counting sort (512 node bins) -> padded ssrc,
// offs/degn/di. 1024 threads/block; stmp read ONCE via register cache.
// (R20: perm removed — R19 showed degree-balance is neutral; gathers are
// latency/MSHR-bound at CU level, and perm cost contiguity.)
// =====================================================================
__global__ __launch_bounds__(1024) void group_sort(const int* __restrict__ scur,
                                                   const unsigned int* __restrict__ stmp,
                                                   unsigned int* __restrict__ ssrc,
                                                   int* __restrict__ offs,
                                                   int* __restrict__ degn,
                                                   float* __restrict__ di) {
    __shared__ int lh[512];
    __shared__ int sc[512];
    __shared__ int lcur[512];
    int g = blockIdx.x;
    int tid = threadIdx.x;
    int base = g * SCAP;
    int cnt = scur[g * 16] - base;
    if (tid < 512) lh[tid] = 0;
    __syncthreads();
    unsigned int uv[9];          // SCAP/1024 == 9 exactly
#pragma unroll
    for (int r = 0; r < 9; r++) {
        int i = tid + r * 1024;
        uv[r] = 0xFFFFFFFFu;     // valid entries are < 2^26, sentinel safe
        if (i < cnt) {
            uv[r] = stmp[base + i];
            atomicAdd(&lh[uv[r] >> 17], 1);
        }
    }
    __syncthreads();
    int h = 0, pd = 0;
    if (tid < 512) {
        h = lh[tid];
        pd = (h + 7) & ~7;
        sc[tid] = pd;
    }
    __syncthreads();
    for (int off = 1; off < 512; off <<= 1) {
        int v = 0;
        if (tid >= off && tid < 512) v = sc[tid - off];
        __syncthreads();
        if (tid < 512) sc[tid] += v;
        __syncthreads();
    }
    if (tid < 512) {
        int excl = sc[tid] - pd;    // exclusive scan of padded counts
        lcur[tid] = excl;
        int node = g * 512 + tid;
        if (node < NN) {
            offs[node] = g * GCAP + excl;
            degn[node] = pd;
            di[node] = rsqrtf((float)h + 1.0f);
        }
        size_t gb = (size_t)g * GCAP;
        for (int q = h; q < pd; q++) ssrc[gb + excl + q] = (unsigned int)NN;  // pads -> zero row
    }
    __syncthreads();
#pragma unroll
    for (int r = 0; r < 9; r++) {
        unsigned int u = uv[r];
        if (u != 0xFFFFFFFFu) {
            int dl = (int)(u >> 17);
            int pos = atomicAdd(&lcur[dl], 1);
            ssrc[(size_t)g * GCAP + pos] = u & 0x1FFFFu;
        }
    }
}

// =====================================================================
// R15: MFMA GEMM 1: hws = half((x @ W_eff + b_eff) * di)  [N,128]@[128,64]
// W^T fp16 held ENTIRELY in per-wave registers -> A streams HBM->MFMA.
// =====================================================================
__global__ __launch_bounds__(256, 4) void gemm1_mfma(const float* __restrict__ x,
                                                     const _Float16* __restrict__ wt,
                                                     const float* __restrict__ beff,
                                                     const float* __restrict__ di,
                                                     __half* __restrict__ hws) {
    __shared__ _Float16 wS[64 * 136];   // [n][k] padded 128->136 (bank-spread)
    int tid = threadIdx.x;
    for (int i = tid; i < 1024; i += 256) {          // 1024 x uint4 = 8192 halves
        int n = i >> 4, k0 = (i & 15) * 8;
        *(uint4*)&wS[n * 136 + k0] = ((const uint4*)wt)[i];
    }
    __syncthreads();
    int wv = tid >> 6, lane = tid & 63;
    int l15 = lane & 15, lg = lane >> 4;
    int rbase = blockIdx.x * 64 + wv * 16;
    if (rbase >= NN) return;                         // NN%16==0: whole-tile skip only
    half8 bf[4][4];                                  // [ks][ns] B-fragments (W), 64 VGPR
#pragma unroll
    for (int ks = 0; ks < 4; ks++)
#pragma unroll
        for (int ns = 0; ns < 4; ns++)
            bf[ks][ns] = *(const half8*)&wS[(ns * 16 + l15) * 136 + ks * 32 + lg * 8];
    floatx4 acc[4];
#pragma unroll
    for (int ns = 0; ns < 4; ns++) acc[ns] = (floatx4){0.f, 0.f, 0.f, 0.f};
    const float* xrow = x + (size_t)(rbase + l15) * FIN;
#pragma unroll
    for (int ks = 0; ks < 4; ks++) {
        float4 lo = *(const float4*)(xrow + ks * 32 + lg * 8);
        float4 hi = *(const float4*)(xrow + ks * 32 + lg * 8 + 4);
        half8 a;
        a[0] = (_Float16)lo.x; a[1] = (_Float16)lo.y; a[2] = (_Float16)lo.z; a[3] = (_Float16)lo.w;
        a[4] = (_Float16)hi.x; a[5] = (_Float16)hi.y; a[6] = (_Float16)hi.z; a[7] = (_Float16)hi.w;
#pragma unroll
        for (int ns = 0; ns < 4; ns++)
            acc[ns] = __builtin_amdgcn_mfma_f32_16x16x32_f16(a, bf[ks][ns], acc[ns], 0, 0, 0);
    }
    int r0 = rbase + lg * 4;
#pragma unroll
    for (int ns = 0; ns < 4; ns++) {
        float be = beff[ns * 16 + l15];
#pragma unroll
        for (int r = 0; r < 4; r++) {
            float dn = di[r0 + r];
            hws[(size_t)(r0 + r) * HD + ns * 16 + l15] = __float2half((acc[ns][r] + be) * dn);
        }
    }
}

// ---------------- gather helpers ----------------
__device__ __forceinline__ RowU ldrow(const __half* __restrict__ hws, unsigned int idx, int fp) {
    RowU r;
    r.f4 = ((const float4*)(hws + (size_t)idx * HD))[fp];
    return r;
}

// R17: spill-proof double-buffered gather core (separately-named scalars,
// unconditional loads in each arm; 16 rows transiently in flight).
#define LDA8(A, B) { u0 = ldrow(hws, (A).x, fp); u1 = ldrow(hws, (A).y, fp); \
                     u2 = ldrow(hws, (A).z, fp); u3 = ldrow(hws, (A).w, fp); \
                     u4 = ldrow(hws, (B).x, fp); u5 = ldrow(hws, (B).y, fp); \
                     u6 = ldrow(hws, (B).z, fp); u7 = ldrow(hws, (B).w, fp); }
#define LDB8(A, B) { v0 = ldrow(hws, (A).x, fp); v1 = ldrow(hws, (A).y, fp); \
                     v2 = ldrow(hws, (A).z, fp); v3 = ldrow(hws, (A).w, fp); \
                     v4 = ldrow(hws, (B).x, fp); v5 = ldrow(hws, (B).y, fp); \
                     v6 = ldrow(hws, (B).z, fp); v7 = ldrow(hws, (B).w, fp); }
#define ACC4(Q, U) { hacc[Q][0] = __hadd2(hacc[Q][0], (U).h2[0]); \
                     hacc[Q][1] = __hadd2(hacc[Q][1], (U).h2[1]); \
                     hacc[Q][2] = __hadd2(hacc[Q][2], (U).h2[2]); \
                     hacc[Q][3] = __hadd2(hacc[Q][3], (U).h2[3]); }
#define ACCA8() { ACC4(0, u0) ACC4(1, u1) ACC4(2, u2) ACC4(3, u3) \
                  ACC4(0, u4) ACC4(1, u5) ACC4(2, u6) ACC4(3, u7) }
#define ACCB8() { ACC4(0, v0) ACC4(1, v1) ACC4(2, v2) ACC4(3, v3) \
                  ACC4(0, v4) ACC4(1, v5) ACC4(2, v6) ACC4(3, v7) }

__device__ __forceinline__ void gather_node8(const int* __restrict__ offs,
                                             const int* __restrict__ pdeg,
                                             const unsigned int* __restrict__ ssrc,
                                             const __half* __restrict__ hws,
                                             int node, int fp, float acc[8]) {
    int i0 = offs[node];
    int deg = pdeg[node];                    // multiple of 8 (may be 0)
    const uint4* ip = (const uint4*)(ssrc + i0);     // 16B-aligned (offs multiple of 8)
    __half2 hacc[4][4];
#pragma unroll
    for (int s = 0; s < 4; s++)
#pragma unroll
        for (int t = 0; t < 4; t++) hacc[s][t] = __floats2half2_rn(0.f, 0.f);
    // self-loop row
    {
        RowU sl = ldrow(hws, (unsigned int)node, fp);
#pragma unroll
        for (int t = 0; t < 4; t++) hacc[0][t] = sl.h2[t];
    }
    int nit = deg >> 3;
    if (nit > 0) {
        RowU u0, u1, u2, u3, u4, u5, u6, u7;
        RowU v0, v1, v2, v3, v4, v5, v6, v7;
        {
            uint4 a = ip[0], b = ip[1];
            LDA8(a, b);
        }
        int it = 1;
        for (; it + 1 < nit; it += 2) {
            uint4 a1 = ip[2 * it], b1 = ip[2 * it + 1];
            LDB8(a1, b1);           // it-th tile loads in flight over ACCA
            ACCA8();
            uint4 a2 = ip[2 * it + 2], b2 = ip[2 * it + 3];
            LDA8(a2, b2);           // (it+1)-th tile loads in flight over ACCB
            ACCB8();
        }
        if (it < nit) {             // one trailing pair: load B, consume A then B
            uint4 a1 = ip[2 * it], b1 = ip[2 * it + 1];
            LDB8(a1, b1);
            ACCA8();
            ACCB8();
        } else {
            ACCA8();
        }
    }
    // combine the 4 half2 sets in fp32
#pragma unroll
    for (int t = 0; t < 4; t++) {
        float2 a = __half22float2(hacc[0][t]);
        float2 b = __half22float2(hacc[1][t]);
        float2 c = __half22float2(hacc[2][t]);
        float2 d = __half22float2(hacc[3][t]);
        acc[2 * t]     = (a.x + b.x) + (c.x + d.x);
        acc[2 * t + 1] = (a.y + b.y) + (c.y + d.y);
    }
}

// LN over the 8-features-per-lane layout; xor 1,2,4 stays inside the
// 8-lane group (lane bits 0..2 == fp). Returns relu'd y[8].
__device__ __forceinline__ void ln8(float v[8], int fp,
                                    const float* __restrict__ g,
                                    const float* __restrict__ bb,
                                    float y[8]) {
    float su = 0.0f;
#pragma unroll
    for (int t = 0; t < 8; t++) su += v[t];
    su += __shfl_xor(su, 1, 64); su += __shfl_xor(su, 2, 64); su += __shfl_xor(su, 4, 64);
    float mu = su * (1.0f / HD);
    float q = 0.0f;
#pragma unroll
    for (int t = 0; t < 8; t++) { float d = v[t] - mu; q += d * d; }
    q += __shfl_xor(q, 1, 64); q += __shfl_xor(q, 2, 64); q += __shfl_xor(q, 4, 64);
    float rstd = rsqrtf(q * (1.0f / HD) + 1e-5f);
    float4 ga = ((const float4*)g)[fp * 2], gb = ((const float4*)g)[fp * 2 + 1];
    float4 ba = ((const float4*)bb)[fp * 2], bc = ((const float4*)bb)[fp * 2 + 1];
    float gv[8] = {ga.x, ga.y, ga.z, ga.w, gb.x, gb.y, gb.z, gb.w};
    float bv[8] = {ba.x, ba.y, ba.z, ba.w, bc.x, bc.y, bc.z, bc.w};
#pragma unroll
    for (int t = 0; t < 8; t++) y[t] = fmaxf((v[t] - mu) * rstd * gv[t] + bv[t], 0.0f);
}

// =====================================================================
// R18 FUSED layer-1 gather + LN + ReLU -> h1, THEN conv2 MFMA -> hws2.
// The block's 32 y-rows are staged in LDS (bit-identical fp16 to the h1
// write); after one barrier each of the 4 waves does a (tile, ns-pair)
// 2x2 MFMA slab vs register-resident c2_w^T and writes hws2 = (y@c2_w)*di.
// =====================================================================
__global__ __launch_bounds__(256, 4) void gather_ln_conv(const int* __restrict__ offs,
                                                         const int* __restrict__ pdeg,
                                                         const unsigned int* __restrict__ ssrc,
                                                         const float* __restrict__ di,
                                                         const __half* __restrict__ hws,
                                                         const float* __restrict__ cb,
                                                         const float* __restrict__ g,
                                                         const float* __restrict__ bb,
                                                         const _Float16* __restrict__ wt2,
                                                         __half* __restrict__ h1out,
                                                         __half* __restrict__ hws2) {
    __shared__ _Float16 wS2[64 * 72];   // c2_w^T [n][k] padded
    __shared__ _Float16 yS[32 * 80];    // 32 y-rows, stride 80 (2-way max on writes)
    int tid = threadIdx.x;
    for (int i = tid; i < 512; i += 256) {           // stage c2_w^T early
        int n = i >> 3, k0 = (i & 7) * 8;
        *(uint4*)&wS2[n * 72 + k0] = ((const uint4*)wt2)[i];
    }
    int wv = tid >> 6;
    int lane = tid & 63;
    int fp = lane & 7, gg = lane >> 3;
    int l15 = lane & 15, lg = lane >> 4;
    int node = blockIdx.x * 32 + wv * 8 + gg;   // NN % 32 == 0
    float acc[8];
    gather_node8(offs, pdeg, ssrc, hws, node, fp, acc);
    float4 ca = ((const float4*)cb)[fp * 2], cc = ((const float4*)cb)[fp * 2 + 1];
    float cv[8] = {ca.x, ca.y, ca.z, ca.w, cc.x, cc.y, cc.z, cc.w};
    float dn = di[node];
    float v[8], y[8];
#pragma unroll
    for (int t = 0; t < 8; t++) v[t] = acc[t] * dn + cv[t];
    ln8(v, fp, g, bb, y);
    union U { float4 f4; __half2 h2[4]; } u;
#pragma unroll
    for (int t = 0; t < 4; t++) u.h2[t] = __floats2half2_rn(y[2 * t], y[2 * t + 1]);
    ((float4*)(h1out + (size_t)node * HD))[fp] = u.f4;   // wave writes 1KB contiguous
    *(float4*)&yS[(wv * 8 + gg) * 80 + fp * 8] = u.f4;   // same bits into LDS
    __syncthreads();
    // ---- conv2 MFMA phase: wave wv -> tile (wv&1), ns pair (wv>>1)*2 ----
    int tile = wv & 1;
    int nsb = (wv >> 1) * 2;
    half8 bf2[2][2];
#pragma unroll
    for (int ks = 0; ks < 2; ks++)
#pragma unroll
        for (int n = 0; n < 2; n++)
            bf2[ks][n] = *(const half8*)&wS2[((nsb + n) * 16 + l15) * 72 + ks * 32 + lg * 8];
    floatx4 acc2[2];
    acc2[0] = (floatx4){0.f, 0.f, 0.f, 0.f};
    acc2[1] = (floatx4){0.f, 0.f, 0.f, 0.f};
    const _Float16* yrow = &yS[(tile * 16 + l15) * 80];
#pragma unroll
    for (int ks = 0; ks < 2; ks++) {
        half8 a = *(const half8*)(yrow + ks * 32 + lg * 8);
#pragma unroll
        for (int n = 0; n < 2; n++)
            acc2[n] = __builtin_amdgcn_mfma_f32_16x16x32_f16(a, bf2[ks][n], acc2[n], 0, 0, 0);
    }
    int r0 = blockIdx.x * 32 + tile * 16 + lg * 4;
#pragma unroll
    for (int n = 0; n < 2; n++) {
#pragma unroll
        for (int r = 0; r < 4; r++) {
            float d2 = di[r0 + r];
            hws2[(size_t)(r0 + r) * HD + (nsb + n) * 16 + l15] = __float2half(acc2[n][r] * d2);
        }
    }
}

// ---------------- layer-2 gather (8 nodes/wave) + LN + ReLU + skip + pooled scatter ----------------
// R14: LDS transpose (stride 65) back to 64-lane CONTIGUOUS atomics.
__global__ __launch_bounds__(256, 4) void gather_ln_pool(const int* __restrict__ offs,
                                                         const int* __restrict__ pdeg,
                                                         const unsigned int* __restrict__ ssrc,
                                                         const float* __restrict__ di,
                                                         const __half* __restrict__ hws,
                                                         const float* __restrict__ cb,
                                                         const float* __restrict__ g,
                                                         const float* __restrict__ bb,
                                                         const __half* __restrict__ h1,
                                                         const int* __restrict__ batch,
                                                         float* __restrict__ readout) {
    __shared__ float ls[32][65];
    __shared__ int lb[32];
    int wv = threadIdx.x >> 6;
    int lane = threadIdx.x & 63;
    int fp = lane & 7, gg = lane >> 3;
    int node = blockIdx.x * 32 + wv * 8 + gg;
    float acc[8];
    gather_node8(offs, pdeg, ssrc, hws, node, fp, acc);
    float4 ca = ((const float4*)cb)[fp * 2], cc = ((const float4*)cb)[fp * 2 + 1];
    float cv[8] = {ca.x, ca.y, ca.z, ca.w, cc.x, cc.y, cc.z, cc.w};
    float dn = di[node];
    float v[8], y[8];
#pragma unroll
    for (int t = 0; t < 8; t++) v[t] = acc[t] * dn + cv[t];
    ln8(v, fp, g, bb, y);
    // skip connection: s = relu(ln(conv2)) + h1
    union U { float4 f4; __half2 h2[4]; } u;
    u.f4 = ((const float4*)(h1 + (size_t)node * HD))[fp];
    int row = wv * 8 + gg;
#pragma unroll
    for (int t = 0; t < 4; t++) {
        float2 p = __half22float2(u.h2[t]);
        ls[row][fp * 8 + 2 * t]     = y[2 * t] + p.x;
        ls[row][fp * 8 + 2 * t + 1] = y[2 * t + 1] + p.y;
    }
    if (fp == 0) lb[row] = batch[node];
    // rows of this wave are wave-private: per-wave DS ordering suffices, no __syncthreads
    int r0 = wv * 8;
    int bu = lb[r0];
    bool uni = true;
#pragma unroll
    for (int r = 1; r < 8; r++) uni = uni && (lb[r0 + r] == bu);
    int f = lane;
    if (uni) {
        float s2 = 0.0f;
#pragma unroll
        for (int r = 0; r < 8; r++) s2 += ls[r0 + r][f];
        atomicAdd(&readout[(size_t)bu * HD + f], s2);   // 64-lane contiguous
    } else {
        // batch sorted within the wave's 8 rows: merge equal runs
        float s2 = ls[r0][f];
        int bprev = lb[r0];
#pragma unroll
        for (int r = 1; r < 8; r++) {
            int bn = lb[r0 + r];
            if (bn == bprev) {
                s2 += ls[r0 + r][f];
            } else {
                atomicAdd(&readout[(size_t)bprev * HD + f], s2);
                s2 = ls[r0 + r][f];
                bprev = bn;
            }
        }
        atomicAdd(&readout[(size_t)bprev * HD + f], s2);
    }
}

// ---------------- final: out = readout @ post_w + post_b  [G,64]@[64,40] ----------------
__global__ __launch_bounds__(256) void out_gemm(const float* __restrict__ r,
                                                const float* __restrict__ w,
                                                const float* __restrict__ b,
                                                float* __restrict__ out) {
    __shared__ float lw[HD * CO];
    for (int i = threadIdx.x; i < HD * CO; i += 256) lw[i] = w[i];
    __syncthreads();
    int grp = blockIdx.x * 4 + (threadIdx.x >> 6);
    int c = threadIdx.x & 63;
    if (grp >= NG || c >= CO) return;
    const float* rr = r + (size_t)grp * HD;
    float acc = b[c];
#pragma unroll 8
    for (int k = 0; k < HD; k++) acc = fmaf(rr[k], lw[k * CO + c], acc);
    out[(size_t)grp * CO + c] = acc;
}

extern "C" void kernel_launch(void* const* d_in, const int* in_sizes, int n_in,
                              void* d_out, int out_size, void* d_ws, size_t ws_size,
                              hipStream_t stream) {
    const float* x      = (const float*)d_in[0];
    const int*   ei     = (const int*)d_in[1];
    const int*   batch  = (const int*)d_in[2];
    const float* pre_w  = (const float*)d_in[3];
    const float* pre_b  = (const float*)d_in[4];
    const float* c1_w   = (const float*)d_in[5];
    const float* c1_b   = (const float*)d_in[6];
    const float* n1_g   = (const float*)d_in[7];
    const float* n1_b   = (const float*)d_in[8];
    const float* c2_w   = (const float*)d_in[9];
    const float* c2_b   = (const float*)d_in[10];
    const float* n2_g   = (const float*)d_in[11];
    const float* n2_b   = (const float*)d_in[12];
    const float* post_w = (const float*)d_in[13];
    const float* post_b = (const float*)d_in[14];

    const int* src = ei;
    const int* dst = ei + NE;

    char* p = (char*)d_ws;
    int*          scur    = (int*)p;          p += (size_t)NSB * 16 * 4;
    int*          offs    = (int*)p;          p += (size_t)NN * 4;
    int*          degn    = (int*)p;          p += (size_t)NN * 4;
    float*        di      = (float*)p;        p += (size_t)NN * 4;
    _Float16*     wth     = (_Float16*)p;     p += (size_t)FIN * HD * 2;   // W_eff^T fp16
    _Float16*     wt2h    = (_Float16*)p;     p += (size_t)HD * HD * 2;    // c2_w^T fp16
    float*        beff    = (float*)p;        p += 256;
    unsigned int* stmp    = (unsigned int*)p; p += (size_t)NSB * SCAP * 4;
    unsigned int* ssrc    = (unsigned int*)p; p += (size_t)NSB * GCAP * 4;
    float*        readout = (float*)p;        p += (size_t)NG * HD * 4;
    __half*       hws     = (__half*)p;       p += (size_t)(NN + 8) * HD * 2;  // +dummy row
    __half*       hws2    = (__half*)p;       p += (size_t)(NN + 8) * HD * 2;  // conv2 out +dummy
    __half*       h1      = (__half*)p;       p += (size_t)NN * HD * 2;

    // setup: cursors, readout zero, dummy rows
    setup_kernel<<<512, 256, 0, stream>>>(scur, readout,
                                          (unsigned int*)(hws + (size_t)NN * HD),
                                          (unsigned int*)(hws2 + (size_t)NN * HD));

    // CSR P1 (+ weight prep hidden in 9 trailing blocks)
    scatter_super<<<NSCAT + 9, 1024, 0, stream>>>(src, dst, scur, stmp,
                                                  pre_w, pre_b, c1_w, c2_w, wth, beff, wt2h);
    // CSR P2
    group_sort<<<NSB, 1024, 0, stream>>>(scur, stmp, ssrc, offs, degn, di);

    // layer 1 GEMM
    gemm1_mfma<<<(NN + 63) / 64, 256, 0, stream>>>(x, wth, beff, di, hws);

    // fused: layer-1 gather + LN + ReLU -> h1, then conv2 MFMA -> hws2
    gather_ln_conv<<<NN / 32, 256, 0, stream>>>(offs, degn, ssrc, di, hws,
                                                c1_b, n1_g, n1_b, wt2h, h1, hws2);

    // layer 2 gather + LN + ReLU + skip + pooled scatter
    gather_ln_pool<<<NN / 32, 256, 0, stream>>>(offs, degn, ssrc, di, hws2,
                                                c2_b, n2_g, n2_b, h1, batch, readout);

    out_gemm<<<(NG + 3) / 4, 256, 0, stream>>>(readout, post_w, post_b, (float*)d_out);
}

// Round 9
// 226.445 us; speedup vs baseline: 1.0208x; 1.0087x over previous
//
#include <hip/hip_runtime.h>
#include <hip/hip_fp16.h>

#define NN 100000
#define NE 1600000
#define FIN 128
#define HD 64
#define CO 40
#define NG 2048
#define NSB 196           // super-buckets of 512 nodes: ceil(100000/512)
#define SCAP 9216         // super-bucket capacity (mean 8163, +11 sigma)
#define GCAP 13312        // padded ssrc capacity per group (SCAP + 512*7 pad)
#define CHUNK 4096        // edges per scatter block
#define NSCAT ((NE + CHUNK - 1) / CHUNK)   // 391

typedef _Float16 half8 __attribute__((ext_vector_type(8)));
typedef float floatx4 __attribute__((ext_vector_type(4)));

union RowU { float4 f4; __half2 h2[4]; };

// ---------------- setup: cursor init only (R21: zeroing moved to group_sort tail) ----------------
__global__ __launch_bounds__(256) void setup_kernel(int* __restrict__ scur) {
    int gid = threadIdx.x;
    if (gid < NSB) scur[gid * 16] = gid * SCAP;
}

// =====================================================================
// P1: binned scatter into 196 super-buckets (512 nodes each).
// 1024 threads/block, (dst,src) register-cached across phases (R13).
// R20: weight prep (wth/beff/wt2h) folded in as 9 trailing blocks.
// =====================================================================
__global__ __launch_bounds__(1024) void scatter_super(const int* __restrict__ src,
                                                      const int* __restrict__ dst,
                                                      int* __restrict__ scur,
                                                      unsigned int* __restrict__ stmp,
                                                      const float* __restrict__ pre_w,
                                                      const float* __restrict__ pre_b,
                                                      const float* __restrict__ c1_w,
                                                      const float* __restrict__ c2_w,
                                                      _Float16* __restrict__ wth,
                                                      float* __restrict__ beff,
                                                      _Float16* __restrict__ wt2h) {
    if (blockIdx.x >= NSCAT) {
        int i = blockIdx.x - NSCAT;
        int tid = threadIdx.x;
        if (i < 8) {
            int o = i * 1024 + tid;          // 8192 wth elements
            int r = o >> 6, c = o & 63;
            float acc = 0.0f;
#pragma unroll 8
            for (int k = 0; k < HD; k++) acc = fmaf(pre_w[r * HD + k], c1_w[k * HD + c], acc);
            wth[c * FIN + r] = (_Float16)acc;
        } else {
#pragma unroll
            for (int j = 0; j < 4; j++) {    // 4096 wt2h elements
                int o = tid + j * 1024;
                int r = o >> 6, c = o & 63;
                wt2h[c * HD + r] = (_Float16)c2_w[o];
            }
            if (tid < HD) {
                float acc = 0.0f;
#pragma unroll 8
                for (int k = 0; k < HD; k++) acc = fmaf(pre_b[k], c1_w[k * HD + tid], acc);
                beff[tid] = acc;
            }
        }
        return;
    }
    __shared__ int hist[NSB];
    __shared__ int gbase[NSB];
    int tid = threadIdx.x;
    int e0 = blockIdx.x * CHUNK;
    int d[4], s[4];
    if (tid < NSB) hist[tid] = 0;
    __syncthreads();
#pragma unroll
    for (int r = 0; r < 4; r++) {
        int e = e0 + tid + r * 1024;
        d[r] = -1; s[r] = 0;
        if (e < NE) {
            d[r] = dst[e];
            s[r] = src[e];
            atomicAdd(&hist[d[r] >> 9], 1);
        }
    }
    __syncthreads();
    if (tid < NSB) {
        int c = hist[tid];
        gbase[tid] = (c > 0) ? atomicAdd(&scur[tid * 16], c) : 0;
        hist[tid] = 0;
    }
    __syncthreads();
#pragma unroll
    for (int r = 0; r < 4; r++) {
        if (d[r] >= 0) {
            int b = d[r] >> 9;
            int p = atomicAdd(&hist[b], 1);
            stmp[gbase[b] + p] = ((unsigned int)(d[r] & 511) << 17) | (unsigned int)s[r];
        }
    }
}

// =====================================================================
// P2: per-super-bucket counting sort (512 node bins) -> padded ssrc,
// offs/degn/di. R21: 18-barrier ladder scan replaced with per-wave
// __shfl_up scan + 8-partial combine (2 barriers); readout/dummy-row
// zeroing folded in as 33 trailing blocks (needed 2 launches later).
// =====================================================================
__global__ __launch_bounds__(1024) void group_sort(const int* __restrict__ scur,
                                                   const unsigned int* __restrict__ stmp,
                                                   unsigned int* __restrict__ ssrc,
                                                   int* __restrict__ offs,
                                                   int* __restrict__ degn,
                                                   float* __restrict__ di,
                                                   float* __restrict__ readout,
                                                   unsigned int* __restrict__ dummy,
                                                   unsigned int* __restrict__ dummy2) {
    int tid = threadIdx.x;
    if (blockIdx.x >= NSB) {
        int i = blockIdx.x - NSB;
        if (i < 32) {
            // readout zero: 131072 floats = 32768 float4 over 32 blocks
            ((float4*)readout)[i * 1024 + tid] = make_float4(0.f, 0.f, 0.f, 0.f);
        } else if (tid < 32) {
            dummy[tid] = 0u; dummy2[tid] = 0u;   // 64 halves = 32 uints each
        }
        return;
    }
    __shared__ int lh[512];
    __shared__ int lcur[512];
    __shared__ int wsum[8];
    int g = blockIdx.x;
    int base = g * SCAP;
    int cnt = scur[g * 16] - base;
    if (tid < 512) lh[tid] = 0;
    __syncthreads();
    unsigned int uv[9];          // SCAP/1024 == 9 exactly
#pragma unroll
    for (int r = 0; r < 9; r++) {
        int i = tid + r * 1024;
        uv[r] = 0xFFFFFFFFu;     // valid entries are < 2^26, sentinel safe
        if (i < cnt) {
            uv[r] = stmp[base + i];
            atomicAdd(&lh[uv[r] >> 17], 1);
        }
    }
    __syncthreads();
    int h = 0, pd = 0;
    if (tid < 512) {
        h = lh[tid];
        pd = (h + 7) & ~7;
    }
    // per-wave inclusive scan of pd (waves 0..7 cover tid<512)
    int lane = tid & 63;
    int incl = pd;
#pragma unroll
    for (int off = 1; off < 64; off <<= 1) {
        int v = __shfl_up(incl, off, 64);
        if (lane >= off) incl += v;
    }
    if (tid < 512 && lane == 63) wsum[tid >> 6] = incl;
    __syncthreads();
    if (tid == 0) {
        int run = 0;
#pragma unroll
        for (int i = 0; i < 8; i++) { int t = wsum[i]; wsum[i] = run; run += t; }
    }
    __syncthreads();
    if (tid < 512) {
        int excl = incl - pd + wsum[tid >> 6];   // exclusive scan of padded counts
        lcur[tid] = excl;
        int node = g * 512 + tid;
        if (node < NN) {
            offs[node] = g * GCAP + excl;
            degn[node] = pd;
            di[node] = rsqrtf((float)h + 1.0f);
        }
        size_t gb = (size_t)g * GCAP;
        for (int q = h; q < pd; q++) ssrc[gb + excl + q] = (unsigned int)NN;  // pads -> zero row
    }
    __syncthreads();
#pragma unroll
    for (int r = 0; r < 9; r++) {
        unsigned int u = uv[r];
        if (u != 0xFFFFFFFFu) {
            int dl = (int)(u >> 17);
            int pos = atomicAdd(&lcur[dl], 1);
            ssrc[(size_t)g * GCAP + pos] = u & 0x1FFFFu;
        }
    }
}

// =====================================================================
// R15: MFMA GEMM 1: hws = half((x @ W_eff + b_eff) * di)  [N,128]@[128,64]
// W^T fp16 held ENTIRELY in per-wave registers -> A streams HBM->MFMA.
// =====================================================================
__global__ __launch_bounds__(256, 4) void gemm1_mfma(const float* __restrict__ x,
                                                     const _Float16* __restrict__ wt,
                                                     const float* __restrict__ beff,
                                                     const float* __restrict__ di,
                                                     __half* __restrict__ hws) {
    __shared__ _Float16 wS[64 * 136];   // [n][k] padded 128->136 (bank-spread)
    int tid = threadIdx.x;
    for (int i = tid; i < 1024; i += 256) {          // 1024 x uint4 = 8192 halves
        int n = i >> 4, k0 = (i & 15) * 8;
        *(uint4*)&wS[n * 136 + k0] = ((const uint4*)wt)[i];
    }
    __syncthreads();
    int wv = tid >> 6, lane = tid & 63;
    int l15 = lane & 15, lg = lane >> 4;
    int rbase = blockIdx.x * 64 + wv * 16;
    if (rbase >= NN) return;                         // NN%16==0: whole-tile skip only
    half8 bf[4][4];                                  // [ks][ns] B-fragments (W), 64 VGPR
#pragma unroll
    for (int ks = 0; ks < 4; ks++)
#pragma unroll
        for (int ns = 0; ns < 4; ns++)
            bf[ks][ns] = *(const half8*)&wS[(ns * 16 + l15) * 136 + ks * 32 + lg * 8];
    floatx4 acc[4];
#pragma unroll
    for (int ns = 0; ns < 4; ns++) acc[ns] = (floatx4){0.f, 0.f, 0.f, 0.f};
    const float* xrow = x + (size_t)(rbase + l15) * FIN;
#pragma unroll
    for (int ks = 0; ks < 4; ks++) {
        float4 lo = *(const float4*)(xrow + ks * 32 + lg * 8);
        float4 hi = *(const float4*)(xrow + ks * 32 + lg * 8 + 4);
        half8 a;
        a[0] = (_Float16)lo.x; a[1] = (_Float16)lo.y; a[2] = (_Float16)lo.z; a[3] = (_Float16)lo.w;
        a[4] = (_Float16)hi.x; a[5] = (_Float16)hi.y; a[6] = (_Float16)hi.z; a[7] = (_Float16)hi.w;
#pragma unroll
        for (int ns = 0; ns < 4; ns++)
            acc[ns] = __builtin_amdgcn_mfma_f32_16x16x32_f16(a, bf[ks][ns], acc[ns], 0, 0, 0);
    }
    int r0 = rbase + lg * 4;
#pragma unroll
    for (int ns = 0; ns < 4; ns++) {
        float be = beff[ns * 16 + l15];
#pragma unroll
        for (int r = 0; r < 4; r++) {
            float dn = di[r0 + r];
            hws[(size_t)(r0 + r) * HD + ns * 16 + l15] = __float2half((acc[ns][r] + be) * dn);
        }
    }
}

// ---------------- gather helpers ----------------
__device__ __forceinline__ RowU ldrow(const __half* __restrict__ hws, unsigned int idx, int fp) {
    RowU r;
    r.f4 = ((const float4*)(hws + (size_t)idx * HD))[fp];
    return r;
}

// R17: spill-proof double-buffered gather core (separately-named scalars,
// unconditional loads in each arm; 16 rows transiently in flight).
#define LDA8(A, B) { u0 = ldrow(hws, (A).x, fp); u1 = ldrow(hws, (A).y, fp); \
                     u2 = ldrow(hws, (A).z, fp); u3 = ldrow(hws, (A).w, fp); \
                     u4 = ldrow(hws, (B).x, fp); u5 = ldrow(hws, (B).y, fp); \
                     u6 = ldrow(hws, (B).z, fp); u7 = ldrow(hws, (B).w, fp); }
#define LDB8(A, B) { v0 = ldrow(hws, (A).x, fp); v1 = ldrow(hws, (A).y, fp); \
                     v2 = ldrow(hws, (A).z, fp); v3 = ldrow(hws, (A).w, fp); \
                     v4 = ldrow(hws, (B).x, fp); v5 = ldrow(hws, (B).y, fp); \
                     v6 = ldrow(hws, (B).z, fp); v7 = ldrow(hws, (B).w, fp); }
#define ACC4(Q, U) { hacc[Q][0] = __hadd2(hacc[Q][0], (U).h2[0]); \
                     hacc[Q][1] = __hadd2(hacc[Q][1], (U).h2[1]); \
                     hacc[Q][2] = __hadd2(hacc[Q][2], (U).h2[2]); \
                     hacc[Q][3] = __hadd2(hacc[Q][3], (U).h2[3]); }
#define ACCA8() { ACC4(0, u0) ACC4(1, u1) ACC4(2, u2) ACC4(3, u3) \
                  ACC4(0, u4) ACC4(1, u5) ACC4(2, u6) ACC4(3, u7) }
#define ACCB8() { ACC4(0, v0) ACC4(1, v1) ACC4(2, v2) ACC4(3, v3) \
                  ACC4(0, v4) ACC4(1, v5) ACC4(2, v6) ACC4(3, v7) }

__device__ __forceinline__ void gather_node8(const int* __restrict__ offs,
                                             const int* __restrict__ pdeg,
                                             const unsigned int* __restrict__ ssrc,
                                             const __half* __restrict__ hws,
                                             int node, int fp, float acc[8]) {
    int i0 = offs[node];
    int deg = pdeg[node];                    // multiple of 8 (may be 0)
    const uint4* ip = (const uint4*)(ssrc + i0);     // 16B-aligned (offs multiple of 8)
    __half2 hacc[4][4];
#pragma unroll
    for (int s = 0; s < 4; s++)
#pragma unroll
        for (int t = 0; t < 4; t++) hacc[s][t] = __floats2half2_rn(0.f, 0.f);
    // self-loop row
    {
        RowU sl = ldrow(hws, (unsigned int)node, fp);
#pragma unroll
        for (int t = 0; t < 4; t++) hacc[0][t] = sl.h2[t];
    }
    int nit = deg >> 3;
    if (nit > 0) {
        RowU u0, u1, u2, u3, u4, u5, u6, u7;
        RowU v0, v1, v2, v3, v4, v5, v6, v7;
        {
            uint4 a = ip[0], b = ip[1];
            LDA8(a, b);
        }
        int it = 1;
        for (; it + 1 < nit; it += 2) {
            uint4 a1 = ip[2 * it], b1 = ip[2 * it + 1];
            LDB8(a1, b1);           // it-th tile loads in flight over ACCA
            ACCA8();
            uint4 a2 = ip[2 * it + 2], b2 = ip[2 * it + 3];
            LDA8(a2, b2);           // (it+1)-th tile loads in flight over ACCB
            ACCB8();
        }
        if (it < nit) {             // one trailing pair: load B, consume A then B
            uint4 a1 = ip[2 * it], b1 = ip[2 * it + 1];
            LDB8(a1, b1);
            ACCA8();
            ACCB8();
        } else {
            ACCA8();
        }
    }
    // combine the 4 half2 sets in fp32
#pragma unroll
    for (int t = 0; t < 4; t++) {
        float2 a = __half22float2(hacc[0][t]);
        float2 b = __half22float2(hacc[1][t]);
        float2 c = __half22float2(hacc[2][t]);
        float2 d = __half22float2(hacc[3][t]);
        acc[2 * t]     = (a.x + b.x) + (c.x + d.x);
        acc[2 * t + 1] = (a.y + b.y) + (c.y + d.y);
    }
}

// LN over the 8-features-per-lane layout; xor 1,2,4 stays inside the
// 8-lane group (lane bits 0..2 == fp). Returns relu'd y[8].
__device__ __forceinline__ void ln8(float v[8], int fp,
                                    const float* __restrict__ g,
                                    const float* __restrict__ bb,
                                    float y[8]) {
    float su = 0.0f;
#pragma unroll
    for (int t = 0; t < 8; t++) su += v[t];
    su += __shfl_xor(su, 1, 64); su += __shfl_xor(su, 2, 64); su += __shfl_xor(su, 4, 64);
    float mu = su * (1.0f / HD);
    float q = 0.0f;
#pragma unroll
    for (int t = 0; t < 8; t++) { float d = v[t] - mu; q += d * d; }
    q += __shfl_xor(q, 1, 64); q += __shfl_xor(q, 2, 64); q += __shfl_xor(q, 4, 64);
    float rstd = rsqrtf(q * (1.0f / HD) + 1e-5f);
    float4 ga = ((const float4*)g)[fp * 2], gb = ((const float4*)g)[fp * 2 + 1];
    float4 ba = ((const float4*)bb)[fp * 2], bc = ((const float4*)bb)[fp * 2 + 1];
    float gv[8] = {ga.x, ga.y, ga.z, ga.w, gb.x, gb.y, gb.z, gb.w};
    float bv[8] = {ba.x, ba.y, ba.z, ba.w, bc.x, bc.y, bc.z, bc.w};
#pragma unroll
    for (int t = 0; t < 8; t++) y[t] = fmaxf((v[t] - mu) * rstd * gv[t] + bv[t], 0.0f);
}

// =====================================================================
// R18 FUSED layer-1 gather + LN + ReLU -> h1, THEN conv2 MFMA -> hws2.
// =====================================================================
__global__ __launch_bounds__(256, 4) void gather_ln_conv(const int* __restrict__ offs,
                                                         const int* __restrict__ pdeg,
                                                         const unsigned int* __restrict__ ssrc,
                                                         const float* __restrict__ di,
                                                         const __half* __restrict__ hws,
                                                         const float* __restrict__ cb,
                                                         const float* __restrict__ g,
                                                         const float* __restrict__ bb,
                                                         const _Float16* __restrict__ wt2,
                                                         __half* __restrict__ h1out,
                                                         __half* __restrict__ hws2) {
    __shared__ _Float16 wS2[64 * 72];   // c2_w^T [n][k] padded
    __shared__ _Float16 yS[32 * 80];    // 32 y-rows, stride 80 (2-way max on writes)
    int tid = threadIdx.x;
    for (int i = tid; i < 512; i += 256) {           // stage c2_w^T early
        int n = i >> 3, k0 = (i & 7) * 8;
        *(uint4*)&wS2[n * 72 + k0] = ((const uint4*)wt2)[i];
    }
    int wv = tid >> 6;
    int lane = tid & 63;
    int fp = lane & 7, gg = lane >> 3;
    int l15 = lane & 15, lg = lane >> 4;
    int node = blockIdx.x * 32 + wv * 8 + gg;   // NN % 32 == 0
    float acc[8];
    gather_node8(offs, pdeg, ssrc, hws, node, fp, acc);
    float4 ca = ((const float4*)cb)[fp * 2], cc = ((const float4*)cb)[fp * 2 + 1];
    float cv[8] = {ca.x, ca.y, ca.z, ca.w, cc.x, cc.y, cc.z, cc.w};
    float dn = di[node];
    float v[8], y[8];
#pragma unroll
    for (int t = 0; t < 8; t++) v[t] = acc[t] * dn + cv[t];
    ln8(v, fp, g, bb, y);
    union U { float4 f4; __half2 h2[4]; } u;
#pragma unroll
    for (int t = 0; t < 4; t++) u.h2[t] = __floats2half2_rn(y[2 * t], y[2 * t + 1]);
    ((float4*)(h1out + (size_t)node * HD))[fp] = u.f4;   // wave writes 1KB contiguous
    *(float4*)&yS[(wv * 8 + gg) * 80 + fp * 8] = u.f4;   // same bits into LDS
    __syncthreads();
    // ---- conv2 MFMA phase: wave wv -> tile (wv&1), ns pair (wv>>1)*2 ----
    int tile = wv & 1;
    int nsb = (wv >> 1) * 2;
    half8 bf2[2][2];
#pragma unroll
    for (int ks = 0; ks < 2; ks++)
#pragma unroll
        for (int n = 0; n < 2; n++)
            bf2[ks][n] = *(const half8*)&wS2[((nsb + n) * 16 + l15) * 72 + ks * 32 + lg * 8];
    floatx4 acc2[2];
    acc2[0] = (floatx4){0.f, 0.f, 0.f, 0.f};
    acc2[1] = (floatx4){0.f, 0.f, 0.f, 0.f};
    const _Float16* yrow = &yS[(tile * 16 + l15) * 80];
#pragma unroll
    for (int ks = 0; ks < 2; ks++) {
        half8 a = *(const half8*)(yrow + ks * 32 + lg * 8);
#pragma unroll
        for (int n = 0; n < 2; n++)
            acc2[n] = __builtin_amdgcn_mfma_f32_16x16x32_f16(a, bf2[ks][n], acc2[n], 0, 0, 0);
    }
    int r0 = blockIdx.x * 32 + tile * 16 + lg * 4;
#pragma unroll
    for (int n = 0; n < 2; n++) {
#pragma unroll
        for (int r = 0; r < 4; r++) {
            float d2 = di[r0 + r];
            hws2[(size_t)(r0 + r) * HD + (nsb + n) * 16 + l15] = __float2half(acc2[n][r] * d2);
        }
    }
}

// ---------------- layer-2 gather (8 nodes/wave) + LN + ReLU + skip + pooled scatter ----------------
// R14: LDS transpose (stride 65) back to 64-lane CONTIGUOUS atomics.
__global__ __launch_bounds__(256, 4) void gather_ln_pool(const int* __restrict__ offs,
                                                         const int* __restrict__ pdeg,
                                                         const unsigned int* __restrict__ ssrc,
                                                         const float* __restrict__ di,
                                                         const __half* __restrict__ hws,
                                                         const float* __restrict__ cb,
                                                         const float* __restrict__ g,
                                                         const float* __restrict__ bb,
                                                         const __half* __restrict__ h1,
                                                         const int* __restrict__ batch,
                                                         float* __restrict__ readout) {
    __shared__ float ls[32][65];
    __shared__ int lb[32];
    int wv = threadIdx.x >> 6;
    int lane = threadIdx.x & 63;
    int fp = lane & 7, gg = lane >> 3;
    int node = blockIdx.x * 32 + wv * 8 + gg;
    float acc[8];
    gather_node8(offs, pdeg, ssrc, hws, node, fp, acc);
    float4 ca = ((const float4*)cb)[fp * 2], cc = ((const float4*)cb)[fp * 2 + 1];
    float cv[8] = {ca.x, ca.y, ca.z, ca.w, cc.x, cc.y, cc.z, cc.w};
    float dn = di[node];
    float v[8], y[8];
#pragma unroll
    for (int t = 0; t < 8; t++) v[t] = acc[t] * dn + cv[t];
    ln8(v, fp, g, bb, y);
    // skip connection: s = relu(ln(conv2)) + h1
    union U { float4 f4; __half2 h2[4]; } u;
    u.f4 = ((const float4*)(h1 + (size_t)node * HD))[fp];
    int row = wv * 8 + gg;
#pragma unroll
    for (int t = 0; t < 4; t++) {
        float2 p = __half22float2(u.h2[t]);
        ls[row][fp * 8 + 2 * t]     = y[2 * t] + p.x;
        ls[row][fp * 8 + 2 * t + 1] = y[2 * t + 1] + p.y;
    }
    if (fp == 0) lb[row] = batch[node];
    // rows of this wave are wave-private: per-wave DS ordering suffices, no __syncthreads
    int r0 = wv * 8;
    int bu = lb[r0];
    bool uni = true;
#pragma unroll
    for (int r = 1; r < 8; r++) uni = uni && (lb[r0 + r] == bu);
    int f = lane;
    if (uni) {
        float s2 = 0.0f;
#pragma unroll
        for (int r = 0; r < 8; r++) s2 += ls[r0 + r][f];
        atomicAdd(&readout[(size_t)bu * HD + f], s2);   // 64-lane contiguous
    } else {
        // batch sorted within the wave's 8 rows: merge equal runs
        float s2 = ls[r0][f];
        int bprev = lb[r0];
#pragma unroll
        for (int r = 1; r < 8; r++) {
            int bn = lb[r0 + r];
            if (bn == bprev) {
                s2 += ls[r0 + r][f];
            } else {
                atomicAdd(&readout[(size_t)bprev * HD + f], s2);
                s2 = ls[r0 + r][f];
                bprev = bn;
            }
        }
        atomicAdd(&readout[(size_t)bprev * HD + f], s2);
    }
}

// ---------------- final: out = readout @ post_w + post_b  [G,64]@[64,40] ----------------
__global__ __launch_bounds__(256) void out_gemm(const float* __restrict__ r,
                                                const float* __restrict__ w,
                                                const float* __restrict__ b,
                                                float* __restrict__ out) {
    __shared__ float lw[HD * CO];
    for (int i = threadIdx.x; i < HD * CO; i += 256) lw[i] = w[i];
    __syncthreads();
    int grp = blockIdx.x * 4 + (threadIdx.x >> 6);
    int c = threadIdx.x & 63;
    if (grp >= NG || c >= CO) return;
    const float* rr = r + (size_t)grp * HD;
    float acc = b[c];
#pragma unroll 8
    for (int k = 0; k < HD; k++) acc = fmaf(rr[k], lw[k * CO + c], acc);
    out[(size_t)grp * CO + c] = acc;
}

extern "C" void kernel_launch(void* const* d_in, const int* in_sizes, int n_in,
                              void* d_out, int out_size, void* d_ws, size_t ws_size,
                              hipStream_t stream) {
    const float* x      = (const float*)d_in[0];
    const int*   ei     = (const int*)d_in[1];
    const int*   batch  = (const int*)d_in[2];
    const float* pre_w  = (const float*)d_in[3];
    const float* pre_b  = (const float*)d_in[4];
    const float* c1_w   = (const float*)d_in[5];
    const float* c1_b   = (const float*)d_in[6];
    const float* n1_g   = (const float*)d_in[7];
    const float* n1_b   = (const float*)d_in[8];
    const float* c2_w   = (const float*)d_in[9];
    const float* c2_b   = (const float*)d_in[10];
    const float* n2_g   = (const float*)d_in[11];
    const float* n2_b   = (const float*)d_in[12];
    const float* post_w = (const float*)d_in[13];
    const float* post_b = (const float*)d_in[14];

    const int* src = ei;
    const int* dst = ei + NE;

    char* p = (char*)d_ws;
    int*          scur    = (int*)p;          p += (size_t)NSB * 16 * 4;
    int*          offs    = (int*)p;          p += (size_t)NN * 4;
    int*          degn    = (int*)p;          p += (size_t)NN * 4;
    float*        di      = (float*)p;        p += (size_t)NN * 4;
    _Float16*     wth     = (_Float16*)p;     p += (size_t)FIN * HD * 2;   // W_eff^T fp16
    _Float16*     wt2h    = (_Float16*)p;     p += (size_t)HD * HD * 2;    // c2_w^T fp16
    float*        beff    = (float*)p;        p += 256;
    unsigned int* stmp    = (unsigned int*)p; p += (size_t)NSB * SCAP * 4;
    unsigned int* ssrc    = (unsigned int*)p; p += (size_t)NSB * GCAP * 4;
    float*        readout = (float*)p;        p += (size_t)NG * HD * 4;
    __half*       hws     = (__half*)p;       p += (size_t)(NN + 8) * HD * 2;  // +dummy row
    __half*       hws2    = (__half*)p;       p += (size_t)(NN + 8) * HD * 2;  // conv2 out +dummy
    __half*       h1      = (__half*)p;       p += (size_t)NN * HD * 2;

    // setup: cursor init only
    setup_kernel<<<1, 256, 0, stream>>>(scur);

    // CSR P1 (+ weight prep hidden in 9 trailing blocks)
    scatter_super<<<NSCAT + 9, 1024, 0, stream>>>(src, dst, scur, stmp,
                                                  pre_w, pre_b, c1_w, c2_w, wth, beff, wt2h);
    // CSR P2 (+ readout/dummy zeroing hidden in 33 trailing blocks)
    group_sort<<<NSB + 33, 1024, 0, stream>>>(scur, stmp, ssrc, offs, degn, di,
                                              readout,
                                              (unsigned int*)(hws + (size_t)NN * HD),
                                              (unsigned int*)(hws2 + (size_t)NN * HD));

    // layer 1 GEMM
    gemm1_mfma<<<(NN + 63) / 64, 256, 0, stream>>>(x, wth, beff, di, hws);

    // fused: layer-1 gather + LN + ReLU -> h1, then conv2 MFMA -> hws2
    gather_ln_conv<<<NN / 32, 256, 0, stream>>>(offs, degn, ssrc, di, hws,
                                                c1_b, n1_g, n1_b, wt2h, h1, hws2);

    // layer 2 gather + LN + ReLU + skip + pooled scatter
    gather_ln_pool<<<NN / 32, 256, 0, stream>>>(offs, degn, ssrc, di, hws2,
                                                c2_b, n2_g, n2_b, h1, batch, readout);

    out_gemm<<<(NG + 3) / 4, 256, 0, stream>>>(readout, post_w, post_b, (float*)d_out);
}